// Round 1
// baseline (227.864 us; speedup 1.0000x reference)
//
#include <hip/hip_runtime.h>

#define B2 2
#define INF 256
#define OUTF 256
#define DEG 16
#define SLOPE 0.2f

// K1: wt_comb[i] = sum_o Wt[i,o]*Wa[256+o]; ws_comb[i] = sum_o Ws[i,o]*Wa[o];
// consts = {bs.Wa_top, bt.Wa_bot}
__global__ __launch_bounds__(256) void combine_weights_k(
    const float* __restrict__ Ws, const float* __restrict__ Wt,
    const float* __restrict__ Wa, const float* __restrict__ bs,
    const float* __restrict__ bt, float* __restrict__ ws_comb,
    float* __restrict__ wt_comb, float* __restrict__ consts) {
  int i = threadIdx.x;
  float s1 = 0.f, s2 = 0.f;
  for (int o = 0; o < OUTF; ++o) {
    s1 += Ws[i * OUTF + o] * Wa[o];
    s2 += Wt[i * OUTF + o] * Wa[OUTF + o];
  }
  ws_comb[i] = s1;
  wt_comb[i] = s2;
  __shared__ float sh0[256], sh1[256];
  sh0[i] = bs[i] * Wa[i];
  sh1[i] = bt[i] * Wa[OUTF + i];
  __syncthreads();
  for (int off = 128; off > 0; off >>= 1) {
    if (i < off) { sh0[i] += sh0[i + off]; sh1[i] += sh1[i + off]; }
    __syncthreads();
  }
  if (i == 0) { consts[0] = sh0[0]; consts[1] = sh1[0]; }
}

// K2: one wave per (node,b) row: as_arr / at_arr = dot(nodes_row, comb) + c
__global__ __launch_bounds__(256) void node_logits_k(
    const float* __restrict__ nodes, const int* __restrict__ usrc,
    const int* __restrict__ utgt, const float* __restrict__ ws_comb,
    const float* __restrict__ wt_comb, const float* __restrict__ consts,
    float* __restrict__ as_arr, float* __restrict__ at_arr,
    int NsB, int NtB) {
  int wave = (blockIdx.x << 2) + (threadIdx.x >> 6);
  int lane = threadIdx.x & 63;
  if (wave >= NsB + NtB) return;
  const float* comb;
  const int* idx;
  float c;
  float* dst;
  int r;
  if (wave < NsB) {
    r = wave; idx = usrc; comb = ws_comb; c = consts[0]; dst = as_arr + r;
  } else {
    r = wave - NsB; idx = utgt; comb = wt_comb; c = consts[1]; dst = at_arr + r;
  }
  int n = r >> 1, b = r & 1;
  long row = (long)idx[n] * B2 + b;
  const float4 a = *(const float4*)(nodes + row * INF + lane * 4);
  const float4 w = *(const float4*)(comb + lane * 4);
  float v = a.x * w.x + a.y * w.y + a.z * w.z + a.w * w.w;
  #pragma unroll
  for (int off = 32; off > 0; off >>= 1) v += __shfl_down(v, off);
  if (lane == 0) *dst = v + c;
}

// K3: per (source s, b): softmax over its 16 contiguous edges
__global__ __launch_bounds__(256) void alpha_k(
    const float* __restrict__ as_arr, const float* __restrict__ at_arr,
    const int* __restrict__ tid_arr, const float* __restrict__ ba,
    float* __restrict__ alpha, int Ns) {
  int g = blockIdx.x * blockDim.x + threadIdx.x;
  int s = g >> 1, b = g & 1;
  if (s >= Ns) return;
  float base = as_arr[s * B2 + b] + ba[0];
  float ex[DEG];
  float den = 0.f;
  #pragma unroll
  for (int j = 0; j < DEG; ++j) {
    int t = tid_arr[s * DEG + j];
    float sc = base + at_arr[t * B2 + b];
    sc = sc > 0.f ? sc : SLOPE * sc;          // leaky_relu
    sc = fminf(2.f, fmaxf(-2.f, sc));          // clip
    float ev = __expf(sc);
    ex[j] = ev;
    den += ev;
  }
  float inv = 1.f / den;
  #pragma unroll
  for (int j = 0; j < DEG; ++j) alpha[(s * DEG + j) * B2 + b] = ex[j] * inv;
}

// K4: C[m, :] = nodes[idx[m/2]*2 + m%2, :] @ W + bias   (M x 256, K=256)
// 64x64 tile, 256 threads, 4x4 per thread, f32 vector FMA
__global__ __launch_bounds__(256) void gemm_gather_k(
    const float* __restrict__ nodes, const int* __restrict__ idx,
    const float* __restrict__ W, const float* __restrict__ bias,
    float* __restrict__ C, int M) {
  __shared__ float As[16][64];   // [k][row]
  __shared__ float Bs[16][64];   // [k][col]
  int t = threadIdx.x;
  int row0 = blockIdx.x * 64, col0 = blockIdx.y * 64;
  int tx = t & 15, ty = t >> 4;
  // A staging: each thread loads float4 at (arow, ak4..ak4+3)
  int arow = t >> 2, ak4 = (t & 3) * 4;
  int m = row0 + arow;
  int mc = m < M ? m : M - 1;
  long nrow = (long)idx[mc >> 1] * B2 + (mc & 1);
  const float* aptr = nodes + nrow * INF + ak4;
  // B staging: each thread loads float4 at (bk, bc4..bc4+3)
  int bk = t >> 4, bc4 = (t & 15) * 4;
  const float* bptr = W + (long)bk * OUTF + col0 + bc4;
  float acc[4][4] = {};
  for (int k0 = 0; k0 < INF; k0 += 16) {
    float4 av = *(const float4*)(aptr + k0);
    float4 bv = *(const float4*)(bptr + (long)k0 * OUTF);
    __syncthreads();   // previous iter's reads done
    As[ak4 + 0][arow] = av.x;
    As[ak4 + 1][arow] = av.y;
    As[ak4 + 2][arow] = av.z;
    As[ak4 + 3][arow] = av.w;
    *(float4*)&Bs[bk][bc4] = bv;
    __syncthreads();
    #pragma unroll
    for (int kk = 0; kk < 16; ++kk) {
      float4 a = *(const float4*)&As[kk][ty * 4];
      float4 b = *(const float4*)&Bs[kk][tx * 4];
      acc[0][0] += a.x * b.x; acc[0][1] += a.x * b.y; acc[0][2] += a.x * b.z; acc[0][3] += a.x * b.w;
      acc[1][0] += a.y * b.x; acc[1][1] += a.y * b.y; acc[1][2] += a.y * b.z; acc[1][3] += a.y * b.w;
      acc[2][0] += a.z * b.x; acc[2][1] += a.z * b.y; acc[2][2] += a.z * b.z; acc[2][3] += a.z * b.w;
      acc[3][0] += a.w * b.x; acc[3][1] += a.w * b.y; acc[3][2] += a.w * b.z; acc[3][3] += a.w * b.w;
    }
  }
  float4 bv = *(const float4*)(bias + col0 + tx * 4);
  #pragma unroll
  for (int i = 0; i < 4; ++i) {
    int mrow = row0 + ty * 4 + i;
    if (mrow >= M) continue;
    float4 o;
    o.x = acc[i][0] + bv.x;
    o.y = acc[i][1] + bv.y;
    o.z = acc[i][2] + bv.z;
    o.w = acc[i][3] + bv.w;
    *(float4*)(C + (long)mrow * OUTF + col0 + tx * 4) = o;
  }
}

// K5: out[s,b,:] += sum_j alpha[tid[e_j],b] * vals[tid[tid[e_j]],b,:]
__global__ __launch_bounds__(256) void aggregate_k(
    const float* __restrict__ vals, const float* __restrict__ alpha,
    const int* __restrict__ tid_arr, float* __restrict__ out) {
  int sb = blockIdx.x;          // s*B + b
  int s = sb >> 1, b = sb & 1;
  int o = threadIdx.x;
  __shared__ int t2s[DEG];
  __shared__ float al[DEG];
  if (o < DEG) {
    int f = tid_arr[s * DEG + o];   // edge index used by the reference quirk
    t2s[o] = tid_arr[f];
    al[o] = alpha[f * B2 + b];
  }
  __syncthreads();
  float acc = out[(long)sb * OUTF + o];
  #pragma unroll
  for (int j = 0; j < DEG; ++j) {
    acc += al[j] * vals[((long)t2s[j] * B2 + b) * OUTF + o];
  }
  out[(long)sb * OUTF + o] = acc;
}

extern "C" void kernel_launch(void* const* d_in, const int* in_sizes, int n_in,
                              void* d_out, int out_size, void* d_ws, size_t ws_size,
                              hipStream_t stream) {
  const float* nodes = (const float*)d_in[0];
  const float* Ws = (const float*)d_in[1];
  const float* bs = (const float*)d_in[2];
  const float* Wt = (const float*)d_in[3];
  const float* bt = (const float*)d_in[4];
  const float* Wv = (const float*)d_in[5];
  const float* bv = (const float*)d_in[6];
  const float* Wa = (const float*)d_in[7];
  const float* ba = (const float*)d_in[8];
  const int* usrc = (const int*)d_in[9];
  const int* utgt = (const int*)d_in[10];
  const int* tidp = (const int*)d_in[12];
  int Ns = in_sizes[9], Nt = in_sizes[10];
  int E = in_sizes[11];
  int NsB = Ns * B2, NtB = Nt * B2;

  float* ws = (float*)d_ws;
  float* vals = ws;                              // NtB * 256
  float* alpha = vals + (size_t)NtB * OUTF;      // E * 2
  float* as_arr = alpha + (size_t)E * B2;        // NsB
  float* at_arr = as_arr + NsB;                  // NtB
  float* ws_comb = at_arr + NtB;                 // 256
  float* wt_comb = ws_comb + 256;                // 256
  float* consts = wt_comb + 256;                 // 2
  float* out = (float*)d_out;

  combine_weights_k<<<1, 256, 0, stream>>>(Ws, Wt, Wa, bs, bt, ws_comb, wt_comb, consts);
  int waves = NsB + NtB;
  node_logits_k<<<(waves + 3) / 4, 256, 0, stream>>>(
      nodes, usrc, utgt, ws_comb, wt_comb, consts, as_arr, at_arr, NsB, NtB);
  alpha_k<<<(NsB + 255) / 256, 256, 0, stream>>>(as_arr, at_arr, tidp, ba, alpha, Ns);
  dim3 g1((NsB + 63) / 64, OUTF / 64);
  gemm_gather_k<<<g1, 256, 0, stream>>>(nodes, usrc, Ws, bs, out, NsB);
  dim3 g2((NtB + 63) / 64, OUTF / 64);
  gemm_gather_k<<<g2, 256, 0, stream>>>(nodes, utgt, Wv, bv, vals, NtB);
  aggregate_k<<<NsB, 256, 0, stream>>>(vals, alpha, tidp, out);
}

// Round 2
// 153.726 us; speedup vs baseline: 1.4823x; 1.4823x over previous
//
#include <hip/hip_runtime.h>

#define B2 2
#define DEG 16
#define SLOPE 0.2f

typedef __attribute__((ext_vector_type(8))) short short8;
typedef __attribute__((ext_vector_type(8))) unsigned short ushort8;
typedef __attribute__((ext_vector_type(4))) unsigned short ushort4v;
typedef __attribute__((ext_vector_type(4))) float f32x4;

__device__ inline unsigned short f2bf(float f) {
  union { float f; unsigned u; } v; v.f = f;
  unsigned r = v.u + 0x7fff + ((v.u >> 16) & 1);   // RNE
  return (unsigned short)(r >> 16);
}
__device__ inline float bf2f(unsigned short u) {
  union { unsigned u; float f; } c; c.u = ((unsigned)u) << 16;
  return c.f;
}

__device__ inline float wave_dot256(const float* __restrict__ a,
                                    const float* __restrict__ b, int lane) {
  float4 x = *(const float4*)(a + lane * 4);
  float4 y = *(const float4*)(b + lane * 4);
  float v = x.x * y.x + x.y * y.y + x.z * y.z + x.w * y.w;
  #pragma unroll
  for (int off = 32; off; off >>= 1) v += __shfl_down(v, off);
  return v;
}

// K0: row-dots: ws_comb[i]=Ws[i,:]·Wa[0:256]; wt_comb[i]=Wt[i,:]·Wa[256:512];
// consts = {bs·Wa_top, bt·Wa_bot}. One wave per row, coalesced.
__global__ __launch_bounds__(256) void combine_weights_k(
    const float* __restrict__ Ws, const float* __restrict__ Wt,
    const float* __restrict__ Wa, const float* __restrict__ bs,
    const float* __restrict__ bt, float* __restrict__ ws_comb,
    float* __restrict__ wt_comb, float* __restrict__ consts) {
  int wave = blockIdx.x * 4 + (threadIdx.x >> 6);
  int lane = threadIdx.x & 63;
  if (wave >= 514) return;
  const float *vec, *wa;
  float* dst;
  if (wave < 256)       { vec = Ws + (long)wave * 256;        wa = Wa;       dst = ws_comb + wave; }
  else if (wave < 512)  { vec = Wt + (long)(wave - 256) * 256; wa = Wa + 256; dst = wt_comb + (wave - 256); }
  else if (wave == 512) { vec = bs; wa = Wa;       dst = consts; }
  else                  { vec = bt; wa = Wa + 256; dst = consts + 1; }
  float v = wave_dot256(vec, wa, lane);
  if (lane == 0) *dst = v;
}

// K1: transpose Ws/Wv [K][N] f32 -> [N][K] bf16 (blockIdx.z selects matrix)
__global__ __launch_bounds__(256) void transpose_w_k(
    const float* __restrict__ Ws, const float* __restrict__ Wv,
    unsigned short* __restrict__ WsT, unsigned short* __restrict__ WvT) {
  const float* src = blockIdx.z ? Wv : Ws;
  unsigned short* dst = blockIdx.z ? WvT : WsT;
  __shared__ float tile[64][65];
  int r0 = blockIdx.x * 64, c0 = blockIdx.y * 64;
  int tr = threadIdx.x >> 6, tc = threadIdx.x & 63;
  #pragma unroll
  for (int i = 0; i < 16; ++i) {
    int r = tr * 16 + i;
    tile[r][tc] = src[(long)(r0 + r) * 256 + c0 + tc];
  }
  __syncthreads();
  #pragma unroll
  for (int i = 0; i < 16; ++i) {
    int r = tr * 16 + i;
    dst[(long)(c0 + r) * 256 + r0 + tc] = f2bf(tile[tc][r]);
  }
}

// K2: convert nodes f32->bf16 AND per-row logits an_s/an_t. One wave per row.
__global__ __launch_bounds__(256) void prep_nodes_k(
    const float* __restrict__ nodes, const float* __restrict__ ws_comb,
    const float* __restrict__ wt_comb, unsigned short* __restrict__ nodes_bf,
    float* __restrict__ an_s, float* __restrict__ an_t, int nrows) {
  int wave = blockIdx.x * 4 + (threadIdx.x >> 6);
  int lane = threadIdx.x & 63;
  if (wave >= nrows) return;
  const float4 a = *(const float4*)(nodes + (long)wave * 256 + lane * 4);
  ushort4v p;
  p[0] = f2bf(a.x); p[1] = f2bf(a.y); p[2] = f2bf(a.z); p[3] = f2bf(a.w);
  *(ushort4v*)(nodes_bf + (long)wave * 256 + lane * 4) = p;
  const float4 w1 = *(const float4*)(ws_comb + lane * 4);
  const float4 w2 = *(const float4*)(wt_comb + lane * 4);
  float vs = a.x * w1.x + a.y * w1.y + a.z * w1.z + a.w * w1.w;
  float vt = a.x * w2.x + a.y * w2.y + a.z * w2.z + a.w * w2.w;
  #pragma unroll
  for (int off = 32; off; off >>= 1) {
    vs += __shfl_down(vs, off);
    vt += __shfl_down(vt, off);
  }
  if (lane == 0) { an_s[wave] = vs; an_t[wave] = vt; }
}

// K3: per (source s, b): softmax over 16 contiguous edges (edges sorted by src)
__global__ __launch_bounds__(256) void alpha_k(
    const float* __restrict__ an_s, const float* __restrict__ an_t,
    const int* __restrict__ usrc, const int* __restrict__ utgt,
    const int* __restrict__ tid_arr, const float* __restrict__ consts,
    const float* __restrict__ ba, float* __restrict__ alpha, int Ns) {
  int g = blockIdx.x * 256 + threadIdx.x;
  int s = g >> 1, b = g & 1;
  if (s >= Ns) return;
  float base = an_s[(long)usrc[s] * B2 + b] + consts[0] + consts[1] + ba[0];
  float ex[DEG];
  float den = 0.f;
  #pragma unroll
  for (int j = 0; j < DEG; ++j) {
    int t = tid_arr[s * DEG + j];
    float sc = base + an_t[(long)utgt[t] * B2 + b];
    sc = sc > 0.f ? sc : SLOPE * sc;
    sc = fminf(2.f, fmaxf(-2.f, sc));
    float ev = __expf(sc);
    ex[j] = ev;
    den += ev;
  }
  float inv = 1.f / den;
  #pragma unroll
  for (int j = 0; j < DEG; ++j) alpha[(long)(s * DEG + j) * B2 + b] = ex[j] * inv;
}

// K4: MFMA GEMM: C[m,:] = gather(nodes_bf)[m,:] @ W + bias. 128x64 tile,
// 4 waves x (32x64 per wave), 16x16x32 bf16 MFMA, f32 accumulate.
// WT is [N][K] bf16 so both frags are contiguous ds_read_b128.
__global__ __launch_bounds__(256, 2) void gemm_mfma_k(
    const unsigned short* __restrict__ Abf, const int* __restrict__ idx,
    const unsigned short* __restrict__ WT, const float* __restrict__ bias,
    float* __restrict__ Cf, unsigned short* __restrict__ Cb, int M) {
  constexpr int LDT = 72;   // pad 64->72 bf16: row stride ≡ 4 banks, phase-clean
  __shared__ unsigned short As[128 * LDT];
  __shared__ unsigned short Bs[64 * LDT];
  int t = threadIdx.x;
  int wv = t >> 6, lane = t & 63;
  int row0 = blockIdx.x * 128, col0 = blockIdx.y * 64;
  int srow = t >> 3;           // 0..31
  int scol = (t & 7) * 8;      // 0..56 (elements)
  const unsigned short* ap[4];
  #pragma unroll
  for (int p = 0; p < 4; ++p) {
    int m = row0 + srow + 32 * p;
    int mc = m < M ? m : M - 1;
    long ar = (long)idx[mc >> 1] * B2 + (mc & 1);
    ap[p] = Abf + ar * 256 + scol;
  }
  const unsigned short* bp0 = WT + (long)(col0 + srow) * 256 + scol;
  const unsigned short* bp1 = WT + (long)(col0 + srow + 32) * 256 + scol;

  f32x4 acc[2][4];
  #pragma unroll
  for (int i = 0; i < 2; ++i)
    #pragma unroll
    for (int j = 0; j < 4; ++j) acc[i][j] = (f32x4)(0.f);

  for (int k0 = 0; k0 < 256; k0 += 64) {
    ushort8 av[4], bv0, bv1;
    #pragma unroll
    for (int p = 0; p < 4; ++p) av[p] = *(const ushort8*)(ap[p] + k0);
    bv0 = *(const ushort8*)(bp0 + k0);
    bv1 = *(const ushort8*)(bp1 + k0);
    __syncthreads();
    #pragma unroll
    for (int p = 0; p < 4; ++p)
      *(ushort8*)&As[(srow + 32 * p) * LDT + scol] = av[p];
    *(ushort8*)&Bs[srow * LDT + scol] = bv0;
    *(ushort8*)&Bs[(srow + 32) * LDT + scol] = bv1;
    __syncthreads();
    #pragma unroll
    for (int ks = 0; ks < 64; ks += 32) {
      int ko = ks + (lane >> 4) * 8;
      short8 af0 = *(const short8*)&As[(32 * wv + (lane & 15)) * LDT + ko];
      short8 af1 = *(const short8*)&As[(32 * wv + 16 + (lane & 15)) * LDT + ko];
      #pragma unroll
      for (int j = 0; j < 4; ++j) {
        short8 bf = *(const short8*)&Bs[(16 * j + (lane & 15)) * LDT + ko];
        acc[0][j] = __builtin_amdgcn_mfma_f32_16x16x32_bf16(af0, bf, acc[0][j], 0, 0, 0);
        acc[1][j] = __builtin_amdgcn_mfma_f32_16x16x32_bf16(af1, bf, acc[1][j], 0, 0, 0);
      }
    }
  }
  // epilogue: C/D layout col=lane&15, row=(lane>>4)*4+reg
  int cq = lane >> 4;
  #pragma unroll
  for (int j = 0; j < 4; ++j) {
    int col = col0 + 16 * j + (lane & 15);
    float bval = bias[col];
    #pragma unroll
    for (int i = 0; i < 2; ++i) {
      #pragma unroll
      for (int r = 0; r < 4; ++r) {
        int row = row0 + 32 * wv + 16 * i + cq * 4 + r;
        if (row < M) {
          float v = acc[i][j][r] + bval;
          if (Cf) Cf[(long)row * 256 + col] = v;
          else    Cb[(long)row * 256 + col] = f2bf(v);
        }
      }
    }
  }
}

// K5: out[s,b,:] += sum_j alpha[tid[e_j],b] * vals[tid[tid[e_j]],b,:]
__global__ __launch_bounds__(256) void aggregate_k(
    const unsigned short* __restrict__ vals, const float* __restrict__ alpha,
    const int* __restrict__ tid_arr, float* __restrict__ out) {
  int sb = blockIdx.x;
  int s = sb >> 1, b = sb & 1;
  int o = threadIdx.x;
  __shared__ int t2s[DEG];
  __shared__ float al[DEG];
  if (o < DEG) {
    int f = tid_arr[s * DEG + o];
    t2s[o] = tid_arr[f];
    al[o] = alpha[(long)f * B2 + b];
  }
  __syncthreads();
  float acc = out[(long)sb * 256 + o];
  #pragma unroll
  for (int j = 0; j < DEG; ++j)
    acc += al[j] * bf2f(vals[((long)t2s[j] * B2 + b) * 256 + o]);
  out[(long)sb * 256 + o] = acc;
}

extern "C" void kernel_launch(void* const* d_in, const int* in_sizes, int n_in,
                              void* d_out, int out_size, void* d_ws, size_t ws_size,
                              hipStream_t stream) {
  const float* nodes = (const float*)d_in[0];
  const float* Ws = (const float*)d_in[1];
  const float* bs = (const float*)d_in[2];
  const float* Wt = (const float*)d_in[3];
  const float* bt = (const float*)d_in[4];
  const float* Wv = (const float*)d_in[5];
  const float* bv = (const float*)d_in[6];
  const float* Wa = (const float*)d_in[7];
  const float* ba = (const float*)d_in[8];
  const int* usrc = (const int*)d_in[9];
  const int* utgt = (const int*)d_in[10];
  const int* tidp = (const int*)d_in[12];
  int Ns = in_sizes[9], Nt = in_sizes[10];
  int E = in_sizes[11];
  int NsB = Ns * B2, NtB = Nt * B2;
  long nrows = in_sizes[0] / 256;   // N_NODES * B2

  unsigned short* nodes_bf = (unsigned short*)d_ws;        // nrows*256
  unsigned short* WsT = nodes_bf + nrows * 256;            // 65536
  unsigned short* WvT = WsT + 65536;                       // 65536
  unsigned short* vals_bf = WvT + 65536;                   // NtB*256
  float* fbase = (float*)(vals_bf + (size_t)NtB * 256);
  float* an_s = fbase;                                     // nrows
  float* an_t = an_s + nrows;                              // nrows
  float* ws_comb = an_t + nrows;                           // 256
  float* wt_comb = ws_comb + 256;                          // 256
  float* consts = wt_comb + 256;                           // 2 (pad 16)
  float* alpha = consts + 16;                              // E*B2
  float* out = (float*)d_out;

  transpose_w_k<<<dim3(4, 4, 2), 256, 0, stream>>>(Ws, Wv, WsT, WvT);
  combine_weights_k<<<129, 256, 0, stream>>>(Ws, Wt, Wa, bs, bt,
                                             ws_comb, wt_comb, consts);
  prep_nodes_k<<<(int)((nrows + 3) / 4), 256, 0, stream>>>(
      nodes, ws_comb, wt_comb, nodes_bf, an_s, an_t, (int)nrows);
  alpha_k<<<(NsB + 255) / 256, 256, 0, stream>>>(
      an_s, an_t, usrc, utgt, tidp, consts, ba, alpha, Ns);
  gemm_mfma_k<<<dim3((NsB + 127) / 128, 4), 256, 0, stream>>>(
      nodes_bf, usrc, WsT, bs, out, nullptr, NsB);
  gemm_mfma_k<<<dim3((NtB + 127) / 128, 4), 256, 0, stream>>>(
      nodes_bf, utgt, WvT, bv, nullptr, vals_bf, NtB);
  aggregate_k<<<NsB, 256, 0, stream>>>(vals_bf, alpha, tidp, out);
}

// Round 3
// 143.920 us; speedup vs baseline: 1.5833x; 1.0681x over previous
//
#include <hip/hip_runtime.h>

#define B2 2
#define DEG 16
#define SLOPE 0.2f

typedef __attribute__((ext_vector_type(8))) short short8;
typedef __attribute__((ext_vector_type(8))) unsigned short ushort8;
typedef __attribute__((ext_vector_type(4))) unsigned short ushort4v;
typedef __attribute__((ext_vector_type(4))) float f32x4;

__device__ inline unsigned short f2bf(float f) {
  union { float f; unsigned u; } v; v.f = f;
  unsigned r = v.u + 0x7fff + ((v.u >> 16) & 1);   // RNE
  return (unsigned short)(r >> 16);
}
__device__ inline float bf2f(unsigned short u) {
  union { unsigned u; float f; } c; c.u = ((unsigned)u) << 16;
  return c.f;
}

__device__ inline float wave_dot256(const float* __restrict__ a,
                                    const float* __restrict__ b, int lane) {
  float4 x = *(const float4*)(a + lane * 4);
  float4 y = *(const float4*)(b + lane * 4);
  float v = x.x * y.x + x.y * y.y + x.z * y.z + x.w * y.w;
  #pragma unroll
  for (int off = 32; off; off >>= 1) v += __shfl_down(v, off);
  return v;
}

// K0 (fused): blocks 0..31 transpose Ws/Wv [K][N]f32 -> [N][K]bf16;
// blocks 32..160: row-dots ws_comb/wt_comb + consts.
__global__ __launch_bounds__(256) void prep_w_k(
    const float* __restrict__ Ws, const float* __restrict__ Wt,
    const float* __restrict__ Wv, const float* __restrict__ Wa,
    const float* __restrict__ bs, const float* __restrict__ bt,
    unsigned short* __restrict__ WsT, unsigned short* __restrict__ WvT,
    float* __restrict__ ws_comb, float* __restrict__ wt_comb,
    float* __restrict__ consts) {
  int bx = blockIdx.x;
  if (bx < 32) {
    const float* src = (bx & 16) ? Wv : Ws;
    unsigned short* dst = (bx & 16) ? WvT : WsT;
    int rc = bx & 15;
    int r0 = (rc >> 2) * 64, c0 = (rc & 3) * 64;
    __shared__ float tile[64][65];
    int tr = threadIdx.x >> 6, tc = threadIdx.x & 63;
    #pragma unroll
    for (int i = 0; i < 16; ++i) {
      int r = tr * 16 + i;
      tile[r][tc] = src[(long)(r0 + r) * 256 + c0 + tc];
    }
    __syncthreads();
    #pragma unroll
    for (int i = 0; i < 16; ++i) {
      int r = tr * 16 + i;
      dst[(long)(c0 + r) * 256 + r0 + tc] = f2bf(tile[tc][r]);
    }
  } else {
    int wave = (bx - 32) * 4 + (threadIdx.x >> 6);
    int lane = threadIdx.x & 63;
    if (wave >= 514) return;
    const float *vec, *wa;
    float* dst;
    if (wave < 256)       { vec = Ws + (long)wave * 256;         wa = Wa;       dst = ws_comb + wave; }
    else if (wave < 512)  { vec = Wt + (long)(wave - 256) * 256; wa = Wa + 256; dst = wt_comb + (wave - 256); }
    else if (wave == 512) { vec = bs; wa = Wa;       dst = consts; }
    else                  { vec = bt; wa = Wa + 256; dst = consts + 1; }
    float v = wave_dot256(vec, wa, lane);
    if (lane == 0) *dst = v;
  }
}

// K1: convert nodes f32->bf16 AND per-row logits an_s/an_t. One wave per row.
__global__ __launch_bounds__(256) void prep_nodes_k(
    const float* __restrict__ nodes, const float* __restrict__ ws_comb,
    const float* __restrict__ wt_comb, unsigned short* __restrict__ nodes_bf,
    float* __restrict__ an_s, float* __restrict__ an_t, int nrows) {
  int wave = blockIdx.x * 4 + (threadIdx.x >> 6);
  int lane = threadIdx.x & 63;
  if (wave >= nrows) return;
  const float4 a = *(const float4*)(nodes + (long)wave * 256 + lane * 4);
  ushort4v p;
  p[0] = f2bf(a.x); p[1] = f2bf(a.y); p[2] = f2bf(a.z); p[3] = f2bf(a.w);
  *(ushort4v*)(nodes_bf + (long)wave * 256 + lane * 4) = p;
  const float4 w1 = *(const float4*)(ws_comb + lane * 4);
  const float4 w2 = *(const float4*)(wt_comb + lane * 4);
  float vs = a.x * w1.x + a.y * w1.y + a.z * w1.z + a.w * w1.w;
  float vt = a.x * w2.x + a.y * w2.y + a.z * w2.z + a.w * w2.w;
  #pragma unroll
  for (int off = 32; off; off >>= 1) {
    vs += __shfl_down(vs, off);
    vt += __shfl_down(vt, off);
  }
  if (lane == 0) { an_s[wave] = vs; an_t[wave] = vt; }
}

// K2: per (source s, b): softmax over 16 contiguous edges (edges sorted by src)
__global__ __launch_bounds__(256) void alpha_k(
    const float* __restrict__ an_s, const float* __restrict__ an_t,
    const int* __restrict__ usrc, const int* __restrict__ utgt,
    const int* __restrict__ tid_arr, const float* __restrict__ consts,
    const float* __restrict__ ba, float* __restrict__ alpha, int Ns) {
  int g = blockIdx.x * 256 + threadIdx.x;
  int s = g >> 1, b = g & 1;
  if (s >= Ns) return;
  float base = an_s[(long)usrc[s] * B2 + b] + consts[0] + consts[1] + ba[0];
  float ex[DEG];
  float den = 0.f;
  #pragma unroll
  for (int j = 0; j < DEG; ++j) {
    int t = tid_arr[s * DEG + j];
    float sc = base + an_t[(long)utgt[t] * B2 + b];
    sc = sc > 0.f ? sc : SLOPE * sc;
    sc = fminf(2.f, fmaxf(-2.f, sc));
    float ev = __expf(sc);
    ex[j] = ev;
    den += ev;
  }
  float inv = 1.f / den;
  #pragma unroll
  for (int j = 0; j < DEG; ++j) alpha[(long)(s * DEG + j) * B2 + b] = ex[j] * inv;
}

// K3: merged MFMA GEMM (z=0: src_proj->out f32; z=1: vals->bf16).
// 128x64 tile, 4 waves x (32x64 per wave), 16x16x32 bf16 MFMA.
__global__ __launch_bounds__(256, 2) void gemm_mfma_k(
    const unsigned short* __restrict__ Abf,
    const int* __restrict__ usrc, const int* __restrict__ utgt,
    const unsigned short* __restrict__ WsT, const unsigned short* __restrict__ WvT,
    const float* __restrict__ bs, const float* __restrict__ bv,
    float* __restrict__ out_f32, unsigned short* __restrict__ vals_bf,
    int Ms, int Mt) {
  bool second = blockIdx.z != 0;
  const int* idx = second ? utgt : usrc;
  const unsigned short* WT = second ? WvT : WsT;
  const float* bias = second ? bv : bs;
  int M = second ? Mt : Ms;
  int row0 = blockIdx.x * 128, col0 = blockIdx.y * 64;
  if (row0 >= M) return;

  constexpr int LDT = 72;
  __shared__ unsigned short As[128 * LDT];
  __shared__ unsigned short Bs[64 * LDT];
  int t = threadIdx.x;
  int wv = t >> 6, lane = t & 63;
  int srow = t >> 3;           // 0..31
  int scol = (t & 7) * 8;      // 0..56
  const unsigned short* ap[4];
  #pragma unroll
  for (int p = 0; p < 4; ++p) {
    int m = row0 + srow + 32 * p;
    int mc = m < M ? m : M - 1;
    long ar = (long)idx[mc >> 1] * B2 + (mc & 1);
    ap[p] = Abf + ar * 256 + scol;
  }
  const unsigned short* bp0 = WT + (long)(col0 + srow) * 256 + scol;
  const unsigned short* bp1 = WT + (long)(col0 + srow + 32) * 256 + scol;

  f32x4 acc[2][4];
  #pragma unroll
  for (int i = 0; i < 2; ++i)
    #pragma unroll
    for (int j = 0; j < 4; ++j) acc[i][j] = (f32x4)(0.f);

  for (int k0 = 0; k0 < 256; k0 += 64) {
    ushort8 av[4], bv0, bv1;
    #pragma unroll
    for (int p = 0; p < 4; ++p) av[p] = *(const ushort8*)(ap[p] + k0);
    bv0 = *(const ushort8*)(bp0 + k0);
    bv1 = *(const ushort8*)(bp1 + k0);
    __syncthreads();
    #pragma unroll
    for (int p = 0; p < 4; ++p)
      *(ushort8*)&As[(srow + 32 * p) * LDT + scol] = av[p];
    *(ushort8*)&Bs[srow * LDT + scol] = bv0;
    *(ushort8*)&Bs[(srow + 32) * LDT + scol] = bv1;
    __syncthreads();
    #pragma unroll
    for (int ks = 0; ks < 64; ks += 32) {
      int ko = ks + (lane >> 4) * 8;
      short8 af0 = *(const short8*)&As[(32 * wv + (lane & 15)) * LDT + ko];
      short8 af1 = *(const short8*)&As[(32 * wv + 16 + (lane & 15)) * LDT + ko];
      #pragma unroll
      for (int j = 0; j < 4; ++j) {
        short8 bf = *(const short8*)&Bs[(16 * j + (lane & 15)) * LDT + ko];
        acc[0][j] = __builtin_amdgcn_mfma_f32_16x16x32_bf16(af0, bf, acc[0][j], 0, 0, 0);
        acc[1][j] = __builtin_amdgcn_mfma_f32_16x16x32_bf16(af1, bf, acc[1][j], 0, 0, 0);
      }
    }
  }
  int cq = lane >> 4;
  #pragma unroll
  for (int j = 0; j < 4; ++j) {
    int col = col0 + 16 * j + (lane & 15);
    float bval = bias[col];
    #pragma unroll
    for (int i = 0; i < 2; ++i) {
      #pragma unroll
      for (int r = 0; r < 4; ++r) {
        int row = row0 + 32 * wv + 16 * i + cq * 4 + r;
        if (row < M) {
          float v = acc[i][j][r] + bval;
          if (!second) out_f32[(long)row * 256 + col] = v;
          else         vals_bf[(long)row * 256 + col] = f2bf(v);
        }
      }
    }
  }
}

// K4: one wave per (s,b): out[s,b,:] += sum_j alpha[f_j,b]*vals[tid[f_j],b,:]
// where f_j = tid[s*16+j]. Vectorized: ushort4 gathers, float4 RMW.
__global__ __launch_bounds__(256) void aggregate_k(
    const unsigned short* __restrict__ vals, const float* __restrict__ alpha,
    const int* __restrict__ tid_arr, float* __restrict__ out, int NsB) {
  int wid = blockIdx.x * 4 + (threadIdx.x >> 6);   // sb index
  int lane = threadIdx.x & 63;
  if (wid >= NsB) return;
  int s = wid >> 1, b = wid & 1;
  int f = tid_arr[s * DEG + (lane & 15)];
  float al = alpha[(long)f * B2 + b];
  int t2 = tid_arr[f];
  float4 acc = *(const float4*)(out + (long)wid * 256 + lane * 4);
  #pragma unroll
  for (int j = 0; j < DEG; ++j) {
    int t2j = __shfl(t2, j);
    float alj = __shfl(al, j);
    ushort4v v = *(const ushort4v*)(vals + ((long)t2j * B2 + b) * 256 + lane * 4);
    acc.x += alj * bf2f(v[0]);
    acc.y += alj * bf2f(v[1]);
    acc.z += alj * bf2f(v[2]);
    acc.w += alj * bf2f(v[3]);
  }
  *(float4*)(out + (long)wid * 256 + lane * 4) = acc;
}

extern "C" void kernel_launch(void* const* d_in, const int* in_sizes, int n_in,
                              void* d_out, int out_size, void* d_ws, size_t ws_size,
                              hipStream_t stream) {
  const float* nodes = (const float*)d_in[0];
  const float* Ws = (const float*)d_in[1];
  const float* bs = (const float*)d_in[2];
  const float* Wt = (const float*)d_in[3];
  const float* bt = (const float*)d_in[4];
  const float* Wv = (const float*)d_in[5];
  const float* bv = (const float*)d_in[6];
  const float* Wa = (const float*)d_in[7];
  const float* ba = (const float*)d_in[8];
  const int* usrc = (const int*)d_in[9];
  const int* utgt = (const int*)d_in[10];
  const int* tidp = (const int*)d_in[12];
  int Ns = in_sizes[9], Nt = in_sizes[10];
  int NsB = Ns * B2, NtB = Nt * B2;
  long nrows = in_sizes[0] / 256;   // N_NODES * B2

  unsigned short* nodes_bf = (unsigned short*)d_ws;        // nrows*256
  unsigned short* WsT = nodes_bf + nrows * 256;            // 65536
  unsigned short* WvT = WsT + 65536;                       // 65536
  unsigned short* vals_bf = WvT + 65536;                   // NtB*256
  float* fbase = (float*)(vals_bf + (size_t)NtB * 256);
  float* an_s = fbase;                                     // nrows
  float* an_t = an_s + nrows;                              // nrows
  float* ws_comb = an_t + nrows;                           // 256
  float* wt_comb = ws_comb + 256;                          // 256
  float* consts = wt_comb + 256;                           // 2 (pad 16)
  float* alpha = consts + 16;                              // E*B2
  float* out = (float*)d_out;

  prep_w_k<<<161, 256, 0, stream>>>(Ws, Wt, Wv, Wa, bs, bt,
                                    WsT, WvT, ws_comb, wt_comb, consts);
  prep_nodes_k<<<(int)((nrows + 3) / 4), 256, 0, stream>>>(
      nodes, ws_comb, wt_comb, nodes_bf, an_s, an_t, (int)nrows);
  alpha_k<<<(NsB + 255) / 256, 256, 0, stream>>>(
      an_s, an_t, usrc, utgt, tidp, consts, ba, alpha, Ns);
  int maxM = NsB > NtB ? NsB : NtB;
  gemm_mfma_k<<<dim3((maxM + 127) / 128, 4, 2), 256, 0, stream>>>(
      nodes_bf, usrc, utgt, WsT, WvT, bs, bv, out, vals_bf, NsB, NtB);
  aggregate_k<<<(NsB + 3) / 4, 256, 0, stream>>>(vals_bf, alpha, tidp, out, NsB);
}

// Round 5
// 137.941 us; speedup vs baseline: 1.6519x; 1.0433x over previous
//
#include <hip/hip_runtime.h>

#define B2 2
#define DEG 16
#define SLOPE 0.2f

typedef __attribute__((ext_vector_type(8))) short short8;
typedef __attribute__((ext_vector_type(8))) unsigned short ushort8;
typedef __attribute__((ext_vector_type(4))) unsigned short ushort4v;
typedef __attribute__((ext_vector_type(4))) float f32x4;

__device__ inline unsigned short f2bf(float f) {
  union { float f; unsigned u; } v; v.f = f;
  unsigned r = v.u + 0x7fff + ((v.u >> 16) & 1);   // RNE
  return (unsigned short)(r >> 16);
}
__device__ inline float bf2f(unsigned short u) {
  union { unsigned u; float f; } c; c.u = ((unsigned)u) << 16;
  return c.f;
}

__device__ inline float wave_dot256(const float* __restrict__ a,
                                    const float* __restrict__ b, int lane) {
  float4 x = *(const float4*)(a + lane * 4);
  float4 y = *(const float4*)(b + lane * 4);
  float v = x.x * y.x + x.y * y.y + x.z * y.z + x.w * y.w;
  #pragma unroll
  for (int off = 32; off; off >>= 1) v += __shfl_down(v, off);
  return v;
}

// K0: blocks 0..31 transpose Ws/Wv [K][N]f32 -> [N][K]bf16;
// blocks 32..160: ws_comb/wt_comb row-dots + consts.
// NOTE: must be a SEPARATE dispatch from prep_nodes_k — prep_nodes reads
// ws_comb/wt_comb (round-4 fusion raced on this, G16).
__global__ __launch_bounds__(256) void prep_w_k(
    const float* __restrict__ Ws, const float* __restrict__ Wt,
    const float* __restrict__ Wv, const float* __restrict__ Wa,
    const float* __restrict__ bs, const float* __restrict__ bt,
    unsigned short* __restrict__ WsT, unsigned short* __restrict__ WvT,
    float* __restrict__ ws_comb, float* __restrict__ wt_comb,
    float* __restrict__ consts) {
  int bx = blockIdx.x;
  if (bx < 32) {
    const float* src = (bx & 16) ? Wv : Ws;
    unsigned short* dst = (bx & 16) ? WvT : WsT;
    int rc = bx & 15;
    int r0 = (rc >> 2) * 64, c0 = (rc & 3) * 64;
    __shared__ float tile[64][65];
    int tr = threadIdx.x >> 6, tc = threadIdx.x & 63;
    #pragma unroll
    for (int i = 0; i < 16; ++i) {
      int r = tr * 16 + i;
      tile[r][tc] = src[(long)(r0 + r) * 256 + c0 + tc];
    }
    __syncthreads();
    #pragma unroll
    for (int i = 0; i < 16; ++i) {
      int r = tr * 16 + i;
      dst[(long)(c0 + r) * 256 + r0 + tc] = f2bf(tile[tc][r]);
    }
  } else {
    int wave = (bx - 32) * 4 + (threadIdx.x >> 6);
    int lane = threadIdx.x & 63;
    if (wave >= 514) return;
    const float *vec, *wa;
    float* dst;
    if (wave < 256)       { vec = Ws + (long)wave * 256;         wa = Wa;       dst = ws_comb + wave; }
    else if (wave < 512)  { vec = Wt + (long)(wave - 256) * 256; wa = Wa + 256; dst = wt_comb + (wave - 256); }
    else if (wave == 512) { vec = bs; wa = Wa;       dst = consts; }
    else                  { vec = bt; wa = Wa + 256; dst = consts + 1; }
    float v = wave_dot256(vec, wa, lane);
    if (lane == 0) *dst = v;
  }
}

// K1: convert nodes f32->bf16 AND per-row logits an_s/an_t. One wave per row.
__global__ __launch_bounds__(256) void prep_nodes_k(
    const float* __restrict__ nodes, const float* __restrict__ ws_comb,
    const float* __restrict__ wt_comb, unsigned short* __restrict__ nodes_bf,
    float* __restrict__ an_s, float* __restrict__ an_t, int nrows) {
  int wave = blockIdx.x * 4 + (threadIdx.x >> 6);
  int lane = threadIdx.x & 63;
  if (wave >= nrows) return;
  const float4 a = *(const float4*)(nodes + (long)wave * 256 + lane * 4);
  ushort4v p;
  p[0] = f2bf(a.x); p[1] = f2bf(a.y); p[2] = f2bf(a.z); p[3] = f2bf(a.w);
  *(ushort4v*)(nodes_bf + (long)wave * 256 + lane * 4) = p;
  const float4 w1 = *(const float4*)(ws_comb + lane * 4);
  const float4 w2 = *(const float4*)(wt_comb + lane * 4);
  float vs = a.x * w1.x + a.y * w1.y + a.z * w1.z + a.w * w1.w;
  float vt = a.x * w2.x + a.y * w2.y + a.z * w2.z + a.w * w2.w;
  #pragma unroll
  for (int off = 32; off; off >>= 1) {
    vs += __shfl_down(vs, off);
    vt += __shfl_down(vt, off);
  }
  if (lane == 0) { an_s[wave] = vs; an_t[wave] = vt; }
}

// K2: merged MFMA GEMM, 128x128 tile, BK=64, 4 waves x (32x128 per wave).
// z=0: src_proj->out f32; z=1: vals->bf16; z=2 (y==0): alpha softmax
// (reads only prev-dispatch outputs an_s/an_t/consts — safe fusion).
__global__ __launch_bounds__(256, 2) void gemm_mfma_k(
    const unsigned short* __restrict__ Abf,
    const int* __restrict__ usrc, const int* __restrict__ utgt,
    const unsigned short* __restrict__ WsT, const unsigned short* __restrict__ WvT,
    const float* __restrict__ bs, const float* __restrict__ bv,
    float* __restrict__ out_f32, unsigned short* __restrict__ vals_bf,
    const float* __restrict__ an_s, const float* __restrict__ an_t,
    const int* __restrict__ tid_arr, const float* __restrict__ consts,
    const float* __restrict__ ba, float* __restrict__ alpha,
    int Ms, int Mt, int Ns) {
  if (blockIdx.z == 2) {
    if (blockIdx.y != 0) return;
    int g = blockIdx.x * 256 + threadIdx.x;
    int s = g >> 1, b = g & 1;
    if (s >= Ns) return;
    float base = an_s[(long)usrc[s] * B2 + b] + consts[0] + consts[1] + ba[0];
    float ex[DEG];
    float den = 0.f;
    #pragma unroll
    for (int j = 0; j < DEG; ++j) {
      int t = tid_arr[s * DEG + j];
      float sc = base + an_t[(long)utgt[t] * B2 + b];
      sc = sc > 0.f ? sc : SLOPE * sc;
      sc = fminf(2.f, fmaxf(-2.f, sc));
      float ev = __expf(sc);
      ex[j] = ev;
      den += ev;
    }
    float inv = 1.f / den;
    #pragma unroll
    for (int j = 0; j < DEG; ++j) alpha[(long)(s * DEG + j) * B2 + b] = ex[j] * inv;
    return;
  }
  bool second = blockIdx.z != 0;
  const int* idx = second ? utgt : usrc;
  const unsigned short* WT = second ? WvT : WsT;
  const float* bias = second ? bv : bs;
  int M = second ? Mt : Ms;
  int row0 = blockIdx.x * 128, col0 = blockIdx.y * 128;
  if (row0 >= M) return;

  constexpr int LDT = 72;
  __shared__ unsigned short As[128 * LDT];
  __shared__ unsigned short Bs[128 * LDT];
  int t = threadIdx.x;
  int wv = t >> 6, lane = t & 63;
  int srow = t >> 3;           // 0..31
  int scol = (t & 7) * 8;      // 0..56
  const unsigned short* ap[4];
  #pragma unroll
  for (int p = 0; p < 4; ++p) {
    int m = row0 + srow + 32 * p;
    int mc = m < M ? m : M - 1;
    long ar = (long)idx[mc >> 1] * B2 + (mc & 1);
    ap[p] = Abf + ar * 256 + scol;
  }
  const unsigned short* bp[4];
  #pragma unroll
  for (int q = 0; q < 4; ++q)
    bp[q] = WT + (long)(col0 + srow + 32 * q) * 256 + scol;

  f32x4 acc[2][8];
  #pragma unroll
  for (int i = 0; i < 2; ++i)
    #pragma unroll
    for (int j = 0; j < 8; ++j) acc[i][j] = (f32x4)(0.f);

  for (int k0 = 0; k0 < 256; k0 += 64) {
    ushort8 av[4], bvv[4];
    #pragma unroll
    for (int p = 0; p < 4; ++p) av[p] = *(const ushort8*)(ap[p] + k0);
    #pragma unroll
    for (int q = 0; q < 4; ++q) bvv[q] = *(const ushort8*)(bp[q] + k0);
    __syncthreads();
    #pragma unroll
    for (int p = 0; p < 4; ++p)
      *(ushort8*)&As[(srow + 32 * p) * LDT + scol] = av[p];
    #pragma unroll
    for (int q = 0; q < 4; ++q)
      *(ushort8*)&Bs[(srow + 32 * q) * LDT + scol] = bvv[q];
    __syncthreads();
    #pragma unroll
    for (int ks = 0; ks < 64; ks += 32) {
      int ko = ks + (lane >> 4) * 8;
      short8 af0 = *(const short8*)&As[(32 * wv + (lane & 15)) * LDT + ko];
      short8 af1 = *(const short8*)&As[(32 * wv + 16 + (lane & 15)) * LDT + ko];
      #pragma unroll
      for (int j = 0; j < 8; ++j) {
        short8 bf = *(const short8*)&Bs[(16 * j + (lane & 15)) * LDT + ko];
        acc[0][j] = __builtin_amdgcn_mfma_f32_16x16x32_bf16(af0, bf, acc[0][j], 0, 0, 0);
        acc[1][j] = __builtin_amdgcn_mfma_f32_16x16x32_bf16(af1, bf, acc[1][j], 0, 0, 0);
      }
    }
  }
  int cq = lane >> 4;
  #pragma unroll
  for (int j = 0; j < 8; ++j) {
    int col = col0 + 16 * j + (lane & 15);
    float bval = bias[col];
    #pragma unroll
    for (int i = 0; i < 2; ++i) {
      #pragma unroll
      for (int r = 0; r < 4; ++r) {
        int row = row0 + 32 * wv + 16 * i + cq * 4 + r;
        if (row < M) {
          float v = acc[i][j][r] + bval;
          if (!second) out_f32[(long)row * 256 + col] = v;
          else         vals_bf[(long)row * 256 + col] = f2bf(v);
        }
      }
    }
  }
}

// K3: one wave per (s,b): out += sum_j alpha[f_j,b]*vals[tid[f_j],b,:].
// ushort8 loads: 2 full rows per instruction (8 VMEM instrs/wave).
__global__ __launch_bounds__(256) void aggregate_k(
    const unsigned short* __restrict__ vals, const float* __restrict__ alpha,
    const int* __restrict__ tid_arr, float* __restrict__ out, int NsB) {
  int wid = blockIdx.x * 4 + (threadIdx.x >> 6);   // sb index
  int lane = threadIdx.x & 63;
  if (wid >= NsB) return;
  int s = wid >> 1, b = wid & 1;
  int f = tid_arr[s * DEG + (lane & 15)];
  float al = alpha[(long)f * B2 + b];
  int t2 = tid_arr[f];
  int half = lane >> 5;
  int colb = (lane & 31) * 8;
  float accv[8] = {0.f, 0.f, 0.f, 0.f, 0.f, 0.f, 0.f, 0.f};
  #pragma unroll
  for (int i = 0; i < 8; ++i) {
    int ra = __shfl(t2, 2 * i), rb = __shfl(t2, 2 * i + 1);
    float aa = __shfl(al, 2 * i), ab = __shfl(al, 2 * i + 1);
    int rr = half ? rb : ra;
    float av = half ? ab : aa;
    ushort8 v = *(const ushort8*)(vals + ((long)rr * B2 + b) * 256 + colb);
    #pragma unroll
    for (int k = 0; k < 8; ++k) accv[k] += av * bf2f(v[k]);
  }
  #pragma unroll
  for (int k = 0; k < 8; ++k) accv[k] += __shfl_xor(accv[k], 32);
  long obase = (long)wid * 256 + colb + half * 4;
  float4 prev = *(const float4*)(out + obase);
  float4 o;
  o.x = prev.x + accv[half * 4 + 0];
  o.y = prev.y + accv[half * 4 + 1];
  o.z = prev.z + accv[half * 4 + 2];
  o.w = prev.w + accv[half * 4 + 3];
  *(float4*)(out + obase) = o;
}

extern "C" void kernel_launch(void* const* d_in, const int* in_sizes, int n_in,
                              void* d_out, int out_size, void* d_ws, size_t ws_size,
                              hipStream_t stream) {
  const float* nodes = (const float*)d_in[0];
  const float* Ws = (const float*)d_in[1];
  const float* bs = (const float*)d_in[2];
  const float* Wt = (const float*)d_in[3];
  const float* bt = (const float*)d_in[4];
  const float* Wv = (const float*)d_in[5];
  const float* bv = (const float*)d_in[6];
  const float* Wa = (const float*)d_in[7];
  const float* ba = (const float*)d_in[8];
  const int* usrc = (const int*)d_in[9];
  const int* utgt = (const int*)d_in[10];
  const int* tidp = (const int*)d_in[12];
  int Ns = in_sizes[9], Nt = in_sizes[10];
  int NsB = Ns * B2, NtB = Nt * B2;
  long nrows = in_sizes[0] / 256;   // N_NODES * B2

  unsigned short* nodes_bf = (unsigned short*)d_ws;        // nrows*256
  unsigned short* WsT = nodes_bf + nrows * 256;            // 65536
  unsigned short* WvT = WsT + 65536;                       // 65536
  unsigned short* vals_bf = WvT + 65536;                   // NtB*256
  float* fbase = (float*)(vals_bf + (size_t)NtB * 256);
  float* an_s = fbase;                                     // nrows
  float* an_t = an_s + nrows;                              // nrows
  float* ws_comb = an_t + nrows;                           // 256
  float* wt_comb = ws_comb + 256;                          // 256
  float* consts = wt_comb + 256;                           // 2 (pad 16)
  float* alpha = consts + 16;                              // E*B2
  float* out = (float*)d_out;

  prep_w_k<<<161, 256, 0, stream>>>(Ws, Wt, Wv, Wa, bs, bt,
                                    WsT, WvT, ws_comb, wt_comb, consts);
  prep_nodes_k<<<(int)((nrows + 3) / 4), 256, 0, stream>>>(
      nodes, ws_comb, wt_comb, nodes_bf, an_s, an_t, (int)nrows);
  int maxM = NsB > NtB ? NsB : NtB;
  gemm_mfma_k<<<dim3((maxM + 127) / 128, 2, 3), 256, 0, stream>>>(
      nodes_bf, usrc, utgt, WsT, WvT, bs, bv, out, vals_bf,
      an_s, an_t, tidp, consts, ba, alpha, NsB, NtB, Ns);
  aggregate_k<<<(NsB + 3) / 4, 256, 0, stream>>>(vals_bf, alpha, tidp, out, NsB);
}

// Round 6
// 136.467 us; speedup vs baseline: 1.6697x; 1.0108x over previous
//
#include <hip/hip_runtime.h>

#define B2 2
#define DEG 16
#define SLOPE 0.2f

typedef __attribute__((ext_vector_type(8))) short short8;
typedef __attribute__((ext_vector_type(8))) unsigned short ushort8;
typedef __attribute__((ext_vector_type(4))) unsigned short ushort4v;
typedef __attribute__((ext_vector_type(4))) float f32x4;

__device__ inline unsigned short f2bf(float f) {
  union { float f; unsigned u; } v; v.f = f;
  unsigned r = v.u + 0x7fff + ((v.u >> 16) & 1);   // RNE
  return (unsigned short)(r >> 16);
}
__device__ inline float bf2f(unsigned short u) {
  union { unsigned u; float f; } c; c.u = ((unsigned)u) << 16;
  return c.f;
}

__device__ inline float wave_dot256(const float* __restrict__ a,
                                    const float* __restrict__ b, int lane) {
  float4 x = *(const float4*)(a + lane * 4);
  float4 y = *(const float4*)(b + lane * 4);
  float v = x.x * y.x + x.y * y.y + x.z * y.z + x.w * y.w;
  #pragma unroll
  for (int off = 32; off; off >>= 1) v += __shfl_down(v, off);
  return v;
}

// D1: combs only (prep_nodes depends on these — must be its own dispatch, G16).
// 514 waves: ws_comb[i]=Ws[i,:]·Wa_top; wt_comb[i]=Wt[i,:]·Wa_bot; consts.
__global__ __launch_bounds__(256) void comb_k(
    const float* __restrict__ Ws, const float* __restrict__ Wt,
    const float* __restrict__ Wa, const float* __restrict__ bs,
    const float* __restrict__ bt, float* __restrict__ ws_comb,
    float* __restrict__ wt_comb, float* __restrict__ consts) {
  int wave = blockIdx.x * 4 + (threadIdx.x >> 6);
  int lane = threadIdx.x & 63;
  if (wave >= 514) return;
  const float *vec, *wa;
  float* dst;
  if (wave < 256)       { vec = Ws + (long)wave * 256;         wa = Wa;       dst = ws_comb + wave; }
  else if (wave < 512)  { vec = Wt + (long)(wave - 256) * 256; wa = Wa + 256; dst = wt_comb + (wave - 256); }
  else if (wave == 512) { vec = bs; wa = Wa;       dst = consts; }
  else                  { vec = bt; wa = Wa + 256; dst = consts + 1; }
  float v = wave_dot256(vec, wa, lane);
  if (lane == 0) *dst = v;
}

// D2: blocks 0..31 transpose Ws/Wv [K][N]f32 -> [N][K]bf16 (no D1 dep);
// blocks 32+: nodes f32->bf16 + per-row logits an_s/an_t (reads D1 combs).
__global__ __launch_bounds__(256) void prep_nodes_k(
    const float* __restrict__ nodes, const float* __restrict__ Ws,
    const float* __restrict__ Wv, const float* __restrict__ ws_comb,
    const float* __restrict__ wt_comb,
    unsigned short* __restrict__ WsT, unsigned short* __restrict__ WvT,
    unsigned short* __restrict__ nodes_bf,
    float* __restrict__ an_s, float* __restrict__ an_t, int nrows) {
  int bx = blockIdx.x;
  if (bx < 32) {
    const float* src = (bx & 16) ? Wv : Ws;
    unsigned short* dst = (bx & 16) ? WvT : WsT;
    int rc = bx & 15;
    int r0 = (rc >> 2) * 64, c0 = (rc & 3) * 64;
    __shared__ float tile[64][65];
    int tr = threadIdx.x >> 6, tc = threadIdx.x & 63;
    #pragma unroll
    for (int i = 0; i < 16; ++i) {
      int r = tr * 16 + i;
      tile[r][tc] = src[(long)(r0 + r) * 256 + c0 + tc];
    }
    __syncthreads();
    #pragma unroll
    for (int i = 0; i < 16; ++i) {
      int r = tr * 16 + i;
      dst[(long)(c0 + r) * 256 + r0 + tc] = f2bf(tile[tc][r]);
    }
    return;
  }
  int wave = (bx - 32) * 4 + (threadIdx.x >> 6);
  int lane = threadIdx.x & 63;
  if (wave >= nrows) return;
  const float4 a = *(const float4*)(nodes + (long)wave * 256 + lane * 4);
  ushort4v p;
  p[0] = f2bf(a.x); p[1] = f2bf(a.y); p[2] = f2bf(a.z); p[3] = f2bf(a.w);
  *(ushort4v*)(nodes_bf + (long)wave * 256 + lane * 4) = p;
  const float4 w1 = *(const float4*)(ws_comb + lane * 4);
  const float4 w2 = *(const float4*)(wt_comb + lane * 4);
  float vs = a.x * w1.x + a.y * w1.y + a.z * w1.z + a.w * w1.w;
  float vt = a.x * w2.x + a.y * w2.y + a.z * w2.z + a.w * w2.w;
  #pragma unroll
  for (int off = 32; off; off >>= 1) {
    vs += __shfl_down(vs, off);
    vt += __shfl_down(vt, off);
  }
  if (lane == 0) { an_s[wave] = vs; an_t[wave] = vt; }
}

// D3: merged MFMA GEMM, 128x128 tile, BK=64, 4 waves x (32x128 per wave).
// z=0: src_proj->out f32; z=1: vals->bf16; z=2 (y==0): alpha softmax
// (reads only prev-dispatch outputs an_s/an_t/consts — safe fusion).
__global__ __launch_bounds__(256, 2) void gemm_mfma_k(
    const unsigned short* __restrict__ Abf,
    const int* __restrict__ usrc, const int* __restrict__ utgt,
    const unsigned short* __restrict__ WsT, const unsigned short* __restrict__ WvT,
    const float* __restrict__ bs, const float* __restrict__ bv,
    float* __restrict__ out_f32, unsigned short* __restrict__ vals_bf,
    const float* __restrict__ an_s, const float* __restrict__ an_t,
    const int* __restrict__ tid_arr, const float* __restrict__ consts,
    const float* __restrict__ ba, float* __restrict__ alpha,
    int Ms, int Mt, int Ns) {
  if (blockIdx.z == 2) {
    if (blockIdx.y != 0) return;
    int g = blockIdx.x * 256 + threadIdx.x;
    int s = g >> 1, b = g & 1;
    if (s >= Ns) return;
    float base = an_s[(long)usrc[s] * B2 + b] + consts[0] + consts[1] + ba[0];
    float ex[DEG];
    float den = 0.f;
    #pragma unroll
    for (int j = 0; j < DEG; ++j) {
      int t = tid_arr[s * DEG + j];
      float sc = base + an_t[(long)utgt[t] * B2 + b];
      sc = sc > 0.f ? sc : SLOPE * sc;
      sc = fminf(2.f, fmaxf(-2.f, sc));
      float ev = __expf(sc);
      ex[j] = ev;
      den += ev;
    }
    float inv = 1.f / den;
    #pragma unroll
    for (int j = 0; j < DEG; ++j) alpha[(long)(s * DEG + j) * B2 + b] = ex[j] * inv;
    return;
  }
  bool second = blockIdx.z != 0;
  const int* idx = second ? utgt : usrc;
  const unsigned short* WT = second ? WvT : WsT;
  const float* bias = second ? bv : bs;
  int M = second ? Mt : Ms;
  int row0 = blockIdx.x * 128, col0 = blockIdx.y * 128;
  if (row0 >= M) return;

  constexpr int LDT = 72;
  __shared__ unsigned short As[128 * LDT];
  __shared__ unsigned short Bs[128 * LDT];
  int t = threadIdx.x;
  int wv = t >> 6, lane = t & 63;
  int srow = t >> 3;           // 0..31
  int scol = (t & 7) * 8;      // 0..56
  const unsigned short* ap[4];
  #pragma unroll
  for (int p = 0; p < 4; ++p) {
    int m = row0 + srow + 32 * p;
    int mc = m < M ? m : M - 1;
    long ar = (long)idx[mc >> 1] * B2 + (mc & 1);
    ap[p] = Abf + ar * 256 + scol;
  }
  const unsigned short* bp[4];
  #pragma unroll
  for (int q = 0; q < 4; ++q)
    bp[q] = WT + (long)(col0 + srow + 32 * q) * 256 + scol;

  f32x4 acc[2][8];
  #pragma unroll
  for (int i = 0; i < 2; ++i)
    #pragma unroll
    for (int j = 0; j < 8; ++j) acc[i][j] = (f32x4)(0.f);

  for (int k0 = 0; k0 < 256; k0 += 64) {
    ushort8 av[4], bvv[4];
    #pragma unroll
    for (int p = 0; p < 4; ++p) av[p] = *(const ushort8*)(ap[p] + k0);
    #pragma unroll
    for (int q = 0; q < 4; ++q) bvv[q] = *(const ushort8*)(bp[q] + k0);
    __syncthreads();
    #pragma unroll
    for (int p = 0; p < 4; ++p)
      *(ushort8*)&As[(srow + 32 * p) * LDT + scol] = av[p];
    #pragma unroll
    for (int q = 0; q < 4; ++q)
      *(ushort8*)&Bs[(srow + 32 * q) * LDT + scol] = bvv[q];
    __syncthreads();
    #pragma unroll
    for (int ks = 0; ks < 64; ks += 32) {
      int ko = ks + (lane >> 4) * 8;
      short8 af0 = *(const short8*)&As[(32 * wv + (lane & 15)) * LDT + ko];
      short8 af1 = *(const short8*)&As[(32 * wv + 16 + (lane & 15)) * LDT + ko];
      #pragma unroll
      for (int j = 0; j < 8; ++j) {
        short8 bf = *(const short8*)&Bs[(16 * j + (lane & 15)) * LDT + ko];
        acc[0][j] = __builtin_amdgcn_mfma_f32_16x16x32_bf16(af0, bf, acc[0][j], 0, 0, 0);
        acc[1][j] = __builtin_amdgcn_mfma_f32_16x16x32_bf16(af1, bf, acc[1][j], 0, 0, 0);
      }
    }
  }
  int cq = lane >> 4;
  #pragma unroll
  for (int j = 0; j < 8; ++j) {
    int col = col0 + 16 * j + (lane & 15);
    float bval = bias[col];
    #pragma unroll
    for (int i = 0; i < 2; ++i) {
      #pragma unroll
      for (int r = 0; r < 4; ++r) {
        int row = row0 + 32 * wv + 16 * i + cq * 4 + r;
        if (row < M) {
          float v = acc[i][j][r] + bval;
          if (!second) out_f32[(long)row * 256 + col] = v;
          else         vals_bf[(long)row * 256 + col] = f2bf(v);
        }
      }
    }
  }
}

// D4: ONE wave per source s covering BOTH batch rows.
// Each gather is a contiguous 1 KB row-pair vals[t2*2+{0,1}][:] (lane*16B);
// lanes 0..31 accumulate b=0, lanes 32..63 b=1. Out RMW is a 2 KB row-pair.
__global__ __launch_bounds__(256) void aggregate_k(
    const unsigned short* __restrict__ vals, const float* __restrict__ alpha,
    const int* __restrict__ tid_arr, float* __restrict__ out, int Ns) {
  int s = blockIdx.x * 4 + (threadIdx.x >> 6);
  int lane = threadIdx.x & 63;
  if (s >= Ns) return;
  int f = tid_arr[s * DEG + (lane & 15)];   // edge id (reference quirk)
  int b = lane >> 5;
  float al = alpha[(long)f * B2 + b];       // alpha for (j=lane&15, b)
  int t2 = tid_arr[f];                      // value row = tid[tid[e]]
  float acc[8] = {0.f, 0.f, 0.f, 0.f, 0.f, 0.f, 0.f, 0.f};
  #pragma unroll
  for (int j = 0; j < DEG; ++j) {
    int rr = __shfl(t2, j);
    float aj = __shfl(al, (lane & 32) + j);  // b-matched alpha for edge j
    ushort8 v = *(const ushort8*)(vals + (long)rr * 512 + lane * 8);
    #pragma unroll
    for (int k = 0; k < 8; ++k) acc[k] += aj * bf2f(v[k]);
  }
  long ob = (long)s * 512 + lane * 8;
  float4 p0 = *(const float4*)(out + ob);
  float4 p1 = *(const float4*)(out + ob + 4);
  p0.x += acc[0]; p0.y += acc[1]; p0.z += acc[2]; p0.w += acc[3];
  p1.x += acc[4]; p1.y += acc[5]; p1.z += acc[6]; p1.w += acc[7];
  *(float4*)(out + ob) = p0;
  *(float4*)(out + ob + 4) = p1;
}

extern "C" void kernel_launch(void* const* d_in, const int* in_sizes, int n_in,
                              void* d_out, int out_size, void* d_ws, size_t ws_size,
                              hipStream_t stream) {
  const float* nodes = (const float*)d_in[0];
  const float* Ws = (const float*)d_in[1];
  const float* bs = (const float*)d_in[2];
  const float* Wt = (const float*)d_in[3];
  const float* bt = (const float*)d_in[4];
  const float* Wv = (const float*)d_in[5];
  const float* bv = (const float*)d_in[6];
  const float* Wa = (const float*)d_in[7];
  const float* ba = (const float*)d_in[8];
  const int* usrc = (const int*)d_in[9];
  const int* utgt = (const int*)d_in[10];
  const int* tidp = (const int*)d_in[12];
  int Ns = in_sizes[9], Nt = in_sizes[10];
  int NsB = Ns * B2, NtB = Nt * B2;
  long nrows = in_sizes[0] / 256;   // N_NODES * B2

  unsigned short* nodes_bf = (unsigned short*)d_ws;        // nrows*256
  unsigned short* WsT = nodes_bf + nrows * 256;            // 65536
  unsigned short* WvT = WsT + 65536;                       // 65536
  unsigned short* vals_bf = WvT + 65536;                   // NtB*256
  float* fbase = (float*)(vals_bf + (size_t)NtB * 256);
  float* an_s = fbase;                                     // nrows
  float* an_t = an_s + nrows;                              // nrows
  float* ws_comb = an_t + nrows;                           // 256
  float* wt_comb = ws_comb + 256;                          // 256
  float* consts = wt_comb + 256;                           // 2 (pad 16)
  float* alpha = consts + 16;                              // E*B2
  float* out = (float*)d_out;

  comb_k<<<129, 256, 0, stream>>>(Ws, Wt, Wa, bs, bt,
                                  ws_comb, wt_comb, consts);
  prep_nodes_k<<<32 + (int)((nrows + 3) / 4), 256, 0, stream>>>(
      nodes, Ws, Wv, ws_comb, wt_comb, WsT, WvT,
      nodes_bf, an_s, an_t, (int)nrows);
  int maxM = NsB > NtB ? NsB : NtB;
  gemm_mfma_k<<<dim3((maxM + 127) / 128, 2, 3), 256, 0, stream>>>(
      nodes_bf, usrc, utgt, WsT, WvT, bs, bv, out, vals_bf,
      an_s, an_t, tidp, consts, ba, alpha, NsB, NtB, Ns);
  aggregate_k<<<(Ns + 3) / 4, 256, 0, stream>>>(vals_bf, alpha, tidp, out, Ns);
}